// Round 16
// baseline (629.874 us; speedup 1.0000x reference)
//
#include <hip/hip_runtime.h>
#include <hip/hip_fp16.h>

// NNUE forward: out = MLP(clip(concat(Wf@w_in^T+b, Bf@w_in^T+b)))
// Big GEMM: M=8192, N=256, K=40960, HBM-bound on the 1.31 GB A stream.
//
// v14 "barrier-free flatmm" (r15 post-mortem: v7-v13 all ~372-394us across
// six orthogonal levers; the one shared trait is block-wide barriers ->
// straggler-jitter theory: barrier cost = max of per-wave variance, so
// halving count (v10) was neutral. This version has ZERO barriers and
// ZERO LDS):
//  - wave = independent strip: 32 M-rows x 256 N-cols, mfma_32x32x16_f16,
//    acc[8] f32x16 (128 regs, AGPR).
//  - W: pre-swizzled B-fragment image (1KB chunks = one (t,cg) fragment,
//    lane*16B); read global->VGPR directly. Redundant reads served by L2
//    (2.6 MB slice per XCD, ~17 TB/s demand < 34 ceiling).
//  - A: unique per wave, 2 dwordx4/k16; double-set pipeline, compiler
//    counted-vmcnt waits only. In-flight 80 KB/CU >> Little's-law 22 KB.
//  - K-rotation t0=(strip*37)%320 kept (v11 +5%).
//  - 256 blocks x 512 thr (8 waves, 2/SIMD at <=256 regs), ks=bid&7=XCD.

#define FEAT 40960
#define PSTRIDE (8192ull * 256ull)
#define KSPLIT 8
#define KCHUNK (FEAT / KSPLIT)   // 5120
#define NSTEP16 320              // k16 steps per ks chunk
#define WWS_BYTES (20480ull * 1024ull)   // 20 MB

using floatx4  = __attribute__((ext_vector_type(4))) float;
using floatx16 = __attribute__((ext_vector_type(16))) float;
using half8    = __attribute__((ext_vector_type(8))) _Float16;

// ---------------------------------------------------------------------------
// W pre-pass: w_in f32 [256][40960] -> W2 f16 B-fragment image.
// Chunk C = (ks*320 + t)*8 + cg  (1 KB): lane l holds B(col = cg*32 + (l&31),
// k = ks*5120 + t*16 + (l>>5)*8 + j), j=0..7 in order.
// Grid 1280: bid -> cg = bid&7, k-window = (bid>>3)*256.
// ---------------------------------------------------------------------------
__global__ __launch_bounds__(256) void nnue_wprep32(
    const float* __restrict__ w_in, _Float16* __restrict__ W2)
{
    const int cg = blockIdx.x & 7;
    const int kw = (blockIdx.x >> 3) * 256;
    const int c  = cg * 32 + (threadIdx.x >> 3);   // global col
    const int j0 = threadIdx.x & 7;
#pragma unroll
    for (int p = 0; p < 4; ++p) {
        const int k = kw + (j0 + 8 * p) * 8;       // 8 consecutive floats
        const float* src = w_in + (size_t)c * FEAT + k;
        floatx4 v0 = *reinterpret_cast<const floatx4*>(src);
        floatx4 v1 = *reinterpret_cast<const floatx4*>(src + 4);
        half8 h;
#pragma unroll
        for (int j = 0; j < 4; ++j) { h[j] = (_Float16)v0[j]; h[4 + j] = (_Float16)v1[j]; }
        const int ks = k / KCHUNK;
        const int t  = (k % KCHUNK) >> 4;
        const int kh = (k >> 3) & 1;
        const int lw = (kh << 5) | (c & 31);
        const size_t C = (size_t)(ks * NSTEP16 + t) * 8 + cg;
        *reinterpret_cast<half8*>((char*)W2 + C * 1024 + lw * 16) = h;
    }
}

// ---------------------------------------------------------------------------
// Barrier-free GEMM. 512 thr = 8 independent waves; grid 256 (1 block/CU).
// wave strip = (bid>>3)*8 + wave (0..255 = 32 M-rows each); ks = bid&7.
// ---------------------------------------------------------------------------
template <typename PT>
__global__ __launch_bounds__(512, 2) void nnue_gemm_v14(
    const float* __restrict__ white, const float* __restrict__ black,
    const _Float16* __restrict__ W2, PT* __restrict__ P)
{
    const int lane = threadIdx.x & 63;
    const int wave = threadIdx.x >> 6;
    const int ks    = blockIdx.x & 7;               // == XCD (round-robin)
    const int strip = (blockIdx.x >> 3) * 8 + wave; // 0..255

    const float* Abase = (strip < 128)
        ? (white + (size_t)strip * 32 * FEAT)
        : (black + (size_t)(strip - 128) * 32 * FEAT);

    const int row   = lane & 31;
    const int khalf = lane >> 5;
    const float* Aptr = Abase + (size_t)row * FEAT + ks * KCHUNK + khalf * 8;
    const char*  Wbase = (const char*)W2 + (size_t)(ks * NSTEP16) * 8192 + lane * 16;

    floatx16 acc[8];
#pragma unroll
    for (int cg = 0; cg < 8; ++cg)
#pragma unroll
        for (int r = 0; r < 16; ++r) acc[cg][r] = 0.f;

    const int t0 = (strip * 37) % NSTEP16;
    auto wrap = [](int x) { return (x >= NSTEP16) ? x - NSTEP16 : x; };

    floatx4 aX0, aX1, aY0, aY1;
    half8   wX[8], wY[8];

    auto issueA = [&](int t, floatx4& a0, floatx4& a1) {
        a0 = *reinterpret_cast<const floatx4*>(Aptr + (size_t)t * 16);
        a1 = *reinterpret_cast<const floatx4*>(Aptr + (size_t)t * 16 + 4);
    };
    auto issueW = [&](int t, half8 (&w)[8]) {
        const char* b = Wbase + (size_t)t * 8192;
#pragma unroll
        for (int cg = 0; cg < 8; ++cg)
            w[cg] = *reinterpret_cast<const half8*>(b + cg * 1024);
    };
    auto consume = [&](floatx4& a0, floatx4& a1, half8 (&w)[8]) {
        half8 af;
#pragma unroll
        for (int j = 0; j < 4; ++j) { af[j] = (_Float16)a0[j]; af[4 + j] = (_Float16)a1[j]; }
#pragma unroll
        for (int cg = 0; cg < 8; ++cg)
            acc[cg] = __builtin_amdgcn_mfma_f32_32x32x16_f16(af, w[cg], acc[cg], 0, 0, 0);
    };

    // prologue: tile i=0 in flight (set X)
    issueA(t0, aX0, aX1);
    issueW(t0, wX);
    // main: 160 double-steps, no barriers anywhere; counted vmcnt only.
    for (int i = 0; i < NSTEP16; i += 2) {
        const int t1 = wrap(t0 + i + 1);
        issueA(t1, aY0, aY1);                    // i+1 <= 319 always valid
        issueW(t1, wY);
        __builtin_amdgcn_sched_barrier(0);
        consume(aX0, aX1, wX);                   // waits X loads (counted)
        if (i + 2 < NSTEP16) {
            const int t2 = wrap(t0 + i + 2);
            issueA(t2, aX0, aX1);
            issueW(t2, wX);
        }
        __builtin_amdgcn_sched_barrier(0);
        consume(aY0, aY1, wY);
    }

    // epilogue: partial C (pre-bias). C/D (m74/m101): col=lane&31,
    // row=(reg&3)+8*(reg>>2)+4*(lane>>5).
    PT* Pb = P + (size_t)ks * PSTRIDE + (size_t)strip * 32 * 256;
#pragma unroll
    for (int cg = 0; cg < 8; ++cg)
#pragma unroll
        for (int r = 0; r < 16; ++r) {
            const int rit = (r & 3) + 8 * (r >> 2) + 4 * khalf;
            Pb[(size_t)rit * 256 + cg * 32 + (lane & 31)] = (PT)acc[cg][r];
        }
}

// ---------------------------------------------------------------------------
// Tail: reduce 8 K-split partials + b_in + clip -> x[.,512], then the 3 tiny
// layers. One block per 32 batch rows.
// ---------------------------------------------------------------------------
template <typename PT>
__global__ __launch_bounds__(256) void nnue_tail(
    const PT* __restrict__ P,
    const float* __restrict__ b_in,
    const float* __restrict__ w_h1, const float* __restrict__ b_h1,
    const float* __restrict__ w_h2, const float* __restrict__ b_h2,
    const float* __restrict__ w_out, const float* __restrict__ b_out,
    float* __restrict__ out)
{
    __shared__ float xs[32][512];
    __shared__ float w1[32][513];
    __shared__ float w2[32][33];
    __shared__ float h1[32][33];
    __shared__ float h2[32][33];
    __shared__ float wo[32];

    const int tid = threadIdx.x;
    const int b0  = blockIdx.x * 32;

    for (int i = tid; i < 32 * 512; i += 256) w1[i >> 9][i & 511] = w_h1[i];
    for (int i = tid; i < 32 * 32; i += 256)  w2[i >> 5][i & 31]  = w_h2[i];
    if (tid < 32) wo[tid] = w_out[tid];

    for (int i = tid; i < 32 * 512; i += 256) {
        const int r = i >> 9, c = i & 511;
        const int persp = c >> 8, n = c & 255;
        const size_t prow = (size_t)(b0 + r) + (persp ? 4096u : 0u);
        float v = 0.f;
#pragma unroll
        for (int s = 0; s < KSPLIT; ++s)
            v += (float)P[(size_t)s * PSTRIDE + prow * 256 + n];
        v += b_in[n];
        xs[r][c] = fminf(fmaxf(v, 0.f), 1.f);
    }
    __syncthreads();

    for (int p = tid; p < 32 * 32; p += 256) {
        const int o = p & 31, r = p >> 5;
        float a = b_h1[o];
        for (int j = 0; j < 512; ++j) a += xs[r][j] * w1[o][j];
        h1[r][o] = fminf(fmaxf(a, 0.f), 1.f);
    }
    __syncthreads();

    for (int p = tid; p < 32 * 32; p += 256) {
        const int o = p & 31, r = p >> 5;
        float a = b_h2[o];
        for (int j = 0; j < 32; ++j) a += h1[r][j] * w2[o][j];
        h2[r][o] = fminf(fmaxf(a, 0.f), 1.f);
    }
    __syncthreads();

    if (tid < 32) {
        float a = b_out[0];
        for (int j = 0; j < 32; ++j) a += h2[tid][j] * wo[j];
        out[b0 + tid] = a;
    }
}

// ---------------------------------------------------------------------------
// Emergency fallback (ws too small): slow but correct, no scratch.
// ---------------------------------------------------------------------------
__global__ __launch_bounds__(256) void nnue_naive(
    const float* __restrict__ white, const float* __restrict__ black,
    const float* __restrict__ w_in, const float* __restrict__ b_in,
    const float* __restrict__ w_h1, const float* __restrict__ b_h1,
    const float* __restrict__ w_h2, const float* __restrict__ b_h2,
    const float* __restrict__ w_out, const float* __restrict__ b_out,
    float* __restrict__ out)
{
    __shared__ float feat[4096];
    __shared__ float xs[512];
    __shared__ float h1s[32];
    __shared__ float h2s[32];
    const int b = blockIdx.x, tid = threadIdx.x;
    float acc0 = 0.f, acc1 = 0.f;
    for (int c = 0; c < FEAT; c += 2048) {
        for (int i = tid; i < 2048; i += 256) {
            feat[i]        = white[(size_t)b * FEAT + c + i];
            feat[2048 + i] = black[(size_t)b * FEAT + c + i];
        }
        __syncthreads();
        const float* wr = w_in + (size_t)tid * FEAT + c;
        for (int k = 0; k < 2048; ++k) {
            const float w = wr[k];
            acc0 += feat[k] * w;
            acc1 += feat[2048 + k] * w;
        }
        __syncthreads();
    }
    xs[tid]       = fminf(fmaxf(acc0 + b_in[tid], 0.f), 1.f);
    xs[256 + tid] = fminf(fmaxf(acc1 + b_in[tid], 0.f), 1.f);
    __syncthreads();
    if (tid < 32) {
        float a = b_h1[tid];
        for (int j = 0; j < 512; ++j) a += xs[j] * w_h1[tid * 512 + j];
        h1s[tid] = fminf(fmaxf(a, 0.f), 1.f);
    }
    __syncthreads();
    if (tid < 32) {
        float a = b_h2[tid];
        for (int j = 0; j < 32; ++j) a += h1s[j] * w_h2[tid * 32 + j];
        h2s[tid] = fminf(fmaxf(a, 0.f), 1.f);
    }
    __syncthreads();
    if (tid == 0) {
        float a = b_out[0];
        for (int j = 0; j < 32; ++j) a += h2s[j] * w_out[j];
        out[b] = a;
    }
}

extern "C" void kernel_launch(void* const* d_in, const int* in_sizes, int n_in,
                              void* d_out, int out_size, void* d_ws, size_t ws_size,
                              hipStream_t stream)
{
    const float* white = (const float*)d_in[0];
    const float* black = (const float*)d_in[1];
    const float* w_in  = (const float*)d_in[2];
    const float* b_in  = (const float*)d_in[3];
    const float* w_h1  = (const float*)d_in[4];
    const float* b_h1  = (const float*)d_in[5];
    const float* w_h2  = (const float*)d_in[6];
    const float* b_h2  = (const float*)d_in[7];
    const float* w_out = (const float*)d_in[8];
    const float* b_out = (const float*)d_in[9];
    float* out = (float*)d_out;

    const size_t pF32 = KSPLIT * PSTRIDE * sizeof(float);     // 64 MB
    const size_t pF16 = KSPLIT * PSTRIDE * sizeof(_Float16);  // 32 MB

    if (ws_size >= pF32 + WWS_BYTES) {
        float* P = (float*)d_ws;
        _Float16* W2 = (_Float16*)((char*)d_ws + pF32);
        nnue_wprep32<<<dim3(1280), 256, 0, stream>>>(w_in, W2);
        nnue_gemm_v14<float><<<dim3(256), 512, 0, stream>>>(white, black, W2, P);
        nnue_tail<float><<<dim3(128), 256, 0, stream>>>(P, b_in, w_h1, b_h1,
                                                        w_h2, b_h2, w_out, b_out, out);
    } else if (ws_size >= pF16 + WWS_BYTES) {
        _Float16* P = (_Float16*)d_ws;
        _Float16* W2 = (_Float16*)((char*)d_ws + pF16);
        nnue_wprep32<<<dim3(1280), 256, 0, stream>>>(w_in, W2);
        nnue_gemm_v14<_Float16><<<dim3(256), 512, 0, stream>>>(white, black, W2, P);
        nnue_tail<_Float16><<<dim3(128), 256, 0, stream>>>(P, b_in, w_h1, b_h1,
                                                           w_h2, b_h2, w_out, b_out, out);
    } else {
        nnue_naive<<<4096, 256, 0, stream>>>(white, black, w_in, b_in, w_h1, b_h1,
                                             w_h2, b_h2, w_out, b_out, out);
    }
}

// Round 17
// 380.304 us; speedup vs baseline: 1.6562x; 1.6562x over previous
//
#include <hip/hip_runtime.h>
#include <hip/hip_fp16.h>

// NNUE forward: out = MLP(clip(concat(Wf@w_in^T+b, Bf@w_in^T+b)))
// Big GEMM: M=8192, N=256, K=40960, HBM-bound on the 1.31 GB A stream.
// fp16 MFMA 16x16x32, f32 accumulate.
//
// v15 = v11 (best, 372us) + two residual cuts:
//  (1) f16 P partials: 32 MB instead of 64 -> saves ~64 MB of P round-trip.
//  (2) s_setprio(1) around the MFMA pair (T5): the two co-resident blocks
//      are phase-desynced by K-rotation -> role diversity, setprio regime.
// v11 base (confirmed): flatmm (wave = 16 rows x 256 cols, acc 16xf4),
// A global->VGPR->cvt->MFMA, W pre-swizzled via global_load_lds, 4 bufs,
// 2 tiles/group, vmcnt(4)+lgkmcnt(0) per group, K-rotation t0=(mb*37)%160,
// KS=8 -> 512 blocks 2/CU, ks=blockIdx&7=XCD.
// Refuted levers (r10-r16): burst length, A-LDS, barrier count, pipeline
// depth, stream count, nt-loads, barrier-free; occupancy register-capped.

#define FEAT 40960
#define PSTRIDE (8192ull * 256ull)
#define KSPLIT 8
#define KCHUNK (FEAT / KSPLIT)   // 5120
#define NSTEP 160
#define WTILE_BYTES 16384        // 256 rows x 32 k x f16, swizzled
#define WWS_BYTES (1280ull * WTILE_BYTES)   // 20 MB

using floatx4 = __attribute__((ext_vector_type(4))) float;
using half8   = __attribute__((ext_vector_type(8))) _Float16;

// ---------------------------------------------------------------------------
// W pre-pass: w_in f32 [256][40960] -> Wws f16, 1280 chunks of 16 KB, each
// the exact swizzled LDS image for one K-step: byte(r, granule g) =
// T*16384 + r*64 + ((g ^ ((r>>1)&3))*16). T = ks*160 + t (ks-major).
// ---------------------------------------------------------------------------
__global__ __launch_bounds__(256) void nnue_wprep(
    const float* __restrict__ w_in, _Float16* __restrict__ Wws)
{
    const int bid = blockIdx.x;                       // 1280
    const int T   = (bid & 7) * NSTEP + (bid >> 3);
    char* base = (char*)Wws + (size_t)T * WTILE_BYTES;
    const int tid = threadIdx.x;
    const int kg0 = T * 32;
#pragma unroll
    for (int i = 0; i < 4; ++i) {
        const int G = tid + i * 256;                  // 0..1023
        const int r = G >> 2, g = G & 3;
        const float* src = w_in + (size_t)r * FEAT + kg0 + g * 8;
        floatx4 v0 = *reinterpret_cast<const floatx4*>(src);
        floatx4 v1 = *reinterpret_cast<const floatx4*>(src + 4);
        half8 h;
#pragma unroll
        for (int j = 0; j < 4; ++j) { h[j] = (_Float16)v0[j]; h[4 + j] = (_Float16)v1[j]; }
        *reinterpret_cast<half8*>(base + r * 64 + ((g ^ ((r >> 1) & 3)) << 4)) = h;
    }
}

// ---------------------------------------------------------------------------
// Primary GEMM: 512 thr = 8 waves, wave strip = 16 rows x 256 cols.
// ---------------------------------------------------------------------------
template <typename PT>
__global__ __launch_bounds__(512, 4) void nnue_gemm_v15(
    const float* __restrict__ white, const float* __restrict__ black,
    const _Float16* __restrict__ Wws, PT* __restrict__ P)
{
    __shared__ __align__(16) _Float16 Ws[4][256 * 32];   // 64 KB

    const int tid  = threadIdx.x;
    const int lane = tid & 63;
    const int wave = tid >> 6;    // 0..7

    const int ks = blockIdx.x & 7;    // == XCD index (round-robin dispatch)
    const int mb = blockIdx.x >> 3;   // 0..63

    const float* Abase = (mb < 32)
        ? (white + (size_t)mb * 128 * FEAT)
        : (black + (size_t)(mb - 32) * 128 * FEAT);

    // K-rotation phase: de-alias DRAM channels across blocks (+5%, r13).
    const int t0 = (mb * 37) % NSTEP;
    auto wrap = [](int x) { return (x >= NSTEP) ? x - NSTEP : x; };  // x < 2*NSTEP

    const int frow = lane & 15;
    const int fhi  = lane >> 4;

    // A: per-lane row = wave*16 + frow; tile t covers k = ks*KCHUNK + t*32
    const float* Aptr = Abase + (size_t)(wave * 16 + frow) * FEAT + fhi * 8
                        + ks * KCHUNK;

    // W LDS read byte offset within a row: (fhi*16) ^ (((frow>>1)&3)<<4)
    const int kb = (fhi * 16) ^ (((frow >> 1) & 3) << 4);

    // W async staging: per-lane global src (pre-swizzled), wave-linear LDS
    const char* wsrc0 = (const char*)Wws + (size_t)(ks * NSTEP) * WTILE_BYTES
                        + wave * 2048 + lane * 16;

    floatx4 acc[16];
    const floatx4 zero = {0.f, 0.f, 0.f, 0.f};
#pragma unroll
    for (int n = 0; n < 16; ++n) acc[n] = zero;

    // two statically-named A prefetch sets, each = one GROUP (2 tiles)
    floatx4 cA0, cA1, cA2, cA3, nA0, nA1, nA2, nA3;

    auto issueW = [&](int t, int wb) {               // t = wrapped tile index
        const char* g = wsrc0 + (size_t)t * WTILE_BYTES;
        char* l = (char*)&Ws[wb][0] + wave * 2048;
        __builtin_amdgcn_global_load_lds(
            (const __attribute__((address_space(1))) unsigned int*)g,
            (__attribute__((address_space(3))) unsigned int*)l, 16, 0, 0);
        __builtin_amdgcn_global_load_lds(
            (const __attribute__((address_space(1))) unsigned int*)(g + 1024),
            (__attribute__((address_space(3))) unsigned int*)(l + 1024), 16, 0, 0);
    };

    auto cvt = [&](const floatx4& a0, const floatx4& a1) {
        half8 h;
#pragma unroll
        for (int j = 0; j < 4; ++j) { h[j] = (_Float16)a0[j]; h[4 + j] = (_Float16)a1[j]; }
        return h;
    };

    auto mfmaStep = [&](int wb, half8 af) {
        const char* wbase = (const char*)&Ws[wb][0];
#pragma unroll
        for (int n = 0; n < 16; ++n) {
            half8 bf = *reinterpret_cast<const half8*>(
                wbase + (n * 16 + frow) * 64 + kb);
            acc[n] = __builtin_amdgcn_mfma_f32_16x16x32_f16(af, bf, acc[n], 0, 0, 0);
        }
    };

    // one group: consume 2 tiles (A in c*, W in rb0/rb1), prefetch the next
    // group's 2 tiles (tw0, tw1 wrapped) into wb0/wb1 and n*.
    auto groupf = [&](int tw0, int tw1,
                      floatx4& c0, floatx4& c1, floatx4& c2, floatx4& c3,
                      floatx4& n0, floatx4& n1, floatx4& n2, floatx4& n3,
                      int rb0, int rb1, int wb0, int wb1) {
        issueW(tw0, wb0);
        issueW(tw1, wb1);
        __builtin_amdgcn_sched_barrier(0);
        n0 = *reinterpret_cast<const floatx4*>(Aptr + (size_t)tw0 * 32);
        n1 = *reinterpret_cast<const floatx4*>(Aptr + (size_t)tw0 * 32 + 4);
        n2 = *reinterpret_cast<const floatx4*>(Aptr + (size_t)tw1 * 32);
        n3 = *reinterpret_cast<const floatx4*>(Aptr + (size_t)tw1 * 32 + 4);
        __builtin_amdgcn_s_setprio(1);         // T5: blocks are phase-desynced
        mfmaStep(rb0, cvt(c0, c1));            // cvt waits its A: counted vmcnt
        mfmaStep(rb1, cvt(c2, c3));
        __builtin_amdgcn_s_setprio(0);
        // retire this group's W (cross-wave LDS visibility after the barrier);
        // keep the 4 A loads in flight across the barrier.
        asm volatile("s_waitcnt vmcnt(4) lgkmcnt(0)" ::: "memory");
        __builtin_amdgcn_s_barrier();
        __builtin_amdgcn_sched_barrier(0);
    };

    // prologue: tiles i=0,1 (wrapped) -> bufs 0,1 retired; their A in regs
    {
        const int p0 = t0;                 // wrap(t0) == t0
        const int p1 = wrap(t0 + 1);
        issueW(p0, 0);
        issueW(p1, 1);
        __builtin_amdgcn_sched_barrier(0);
        cA0 = *reinterpret_cast<const floatx4*>(Aptr + (size_t)p0 * 32);
        cA1 = *reinterpret_cast<const floatx4*>(Aptr + (size_t)p0 * 32 + 4);
        cA2 = *reinterpret_cast<const floatx4*>(Aptr + (size_t)p1 * 32);
        cA3 = *reinterpret_cast<const floatx4*>(Aptr + (size_t)p1 * 32 + 4);
        asm volatile("s_waitcnt vmcnt(4)" ::: "memory");   // W(i0),W(i1) retired
        __builtin_amdgcn_s_barrier();
        __builtin_amdgcn_sched_barrier(0);
    }

    // groups 0..77 (39 even/odd pairs); group g prefetches iterations 2g+2,2g+3
    for (int p = 0; p < 39; ++p) {
        const int i0 = 4 * p;
        groupf(wrap(t0 + i0 + 2), wrap(t0 + i0 + 3),
               cA0, cA1, cA2, cA3, nA0, nA1, nA2, nA3, 0, 1, 2, 3);
        groupf(wrap(t0 + i0 + 4), wrap(t0 + i0 + 5),
               nA0, nA1, nA2, nA3, cA0, cA1, cA2, cA3, 2, 3, 0, 1);
    }
    // group 78: reads bufs 0,1 (iters 156,157); prefetch iters 158,159
    groupf(wrap(t0 + 158), wrap(t0 + 159),
           cA0, cA1, cA2, cA3, nA0, nA1, nA2, nA3, 0, 1, 2, 3);
    // group 79 tail: iters 158 (buf 2), 159 (buf 3)
    mfmaStep(2, cvt(nA0, nA1));
    mfmaStep(3, cvt(nA2, nA3));

    // epilogue: partial C. row = wave*16 + fhi*4 + r, col = n*16 + frow
    PT* Pb = P + (size_t)ks * PSTRIDE + (size_t)mb * 128 * 256;
#pragma unroll
    for (int n = 0; n < 16; ++n)
#pragma unroll
        for (int r = 0; r < 4; ++r) {
            const int row = wave * 16 + fhi * 4 + r;
            const int col = n * 16 + frow;
            Pb[(size_t)row * 256 + col] = (PT)acc[n][r];
        }
}

// ---------------------------------------------------------------------------
// Tail: reduce KS partials + b_in + clip -> x[.,512], then the 3 tiny layers.
// One block per 32 batch rows.
// ---------------------------------------------------------------------------
template <typename PT>
__global__ __launch_bounds__(256) void nnue_tail(
    const PT* __restrict__ P,
    const float* __restrict__ b_in,
    const float* __restrict__ w_h1, const float* __restrict__ b_h1,
    const float* __restrict__ w_h2, const float* __restrict__ b_h2,
    const float* __restrict__ w_out, const float* __restrict__ b_out,
    float* __restrict__ out)
{
    __shared__ float xs[32][512];
    __shared__ float w1[32][513];
    __shared__ float w2[32][33];
    __shared__ float h1[32][33];
    __shared__ float h2[32][33];
    __shared__ float wo[32];

    const int tid = threadIdx.x;
    const int b0  = blockIdx.x * 32;

    for (int i = tid; i < 32 * 512; i += 256) w1[i >> 9][i & 511] = w_h1[i];
    for (int i = tid; i < 32 * 32; i += 256)  w2[i >> 5][i & 31]  = w_h2[i];
    if (tid < 32) wo[tid] = w_out[tid];

    for (int i = tid; i < 32 * 512; i += 256) {
        const int r = i >> 9, c = i & 511;
        const int persp = c >> 8, n = c & 255;
        const size_t prow = (size_t)(b0 + r) + (persp ? 4096u : 0u);
        float v = 0.f;
#pragma unroll
        for (int s = 0; s < KSPLIT; ++s)
            v += (float)P[(size_t)s * PSTRIDE + prow * 256 + n];
        v += b_in[n];
        xs[r][c] = fminf(fmaxf(v, 0.f), 1.f);
    }
    __syncthreads();

    for (int p = tid; p < 32 * 32; p += 256) {
        const int o = p & 31, r = p >> 5;
        float a = b_h1[o];
        for (int j = 0; j < 512; ++j) a += xs[r][j] * w1[o][j];
        h1[r][o] = fminf(fmaxf(a, 0.f), 1.f);
    }
    __syncthreads();

    for (int p = tid; p < 32 * 32; p += 256) {
        const int o = p & 31, r = p >> 5;
        float a = b_h2[o];
        for (int j = 0; j < 32; ++j) a += h1[r][j] * w2[o][j];
        h2[r][o] = fminf(fmaxf(a, 0.f), 1.f);
    }
    __syncthreads();

    if (tid < 32) {
        float a = b_out[0];
        for (int j = 0; j < 32; ++j) a += h2[tid][j] * wo[j];
        out[b0 + tid] = a;
    }
}

// ---------------------------------------------------------------------------
// Emergency fallback (ws too small): slow but correct, no scratch.
// ---------------------------------------------------------------------------
__global__ __launch_bounds__(256) void nnue_naive(
    const float* __restrict__ white, const float* __restrict__ black,
    const float* __restrict__ w_in, const float* __restrict__ b_in,
    const float* __restrict__ w_h1, const float* __restrict__ b_h1,
    const float* __restrict__ w_h2, const float* __restrict__ b_h2,
    const float* __restrict__ w_out, const float* __restrict__ b_out,
    float* __restrict__ out)
{
    __shared__ float feat[4096];
    __shared__ float xs[512];
    __shared__ float h1s[32];
    __shared__ float h2s[32];
    const int b = blockIdx.x, tid = threadIdx.x;
    float acc0 = 0.f, acc1 = 0.f;
    for (int c = 0; c < FEAT; c += 2048) {
        for (int i = tid; i < 2048; i += 256) {
            feat[i]        = white[(size_t)b * FEAT + c + i];
            feat[2048 + i] = black[(size_t)b * FEAT + c + i];
        }
        __syncthreads();
        const float* wr = w_in + (size_t)tid * FEAT + c;
        for (int k = 0; k < 2048; ++k) {
            const float w = wr[k];
            acc0 += feat[k] * w;
            acc1 += feat[2048 + k] * w;
        }
        __syncthreads();
    }
    xs[tid]       = fminf(fmaxf(acc0 + b_in[tid], 0.f), 1.f);
    xs[256 + tid] = fminf(fmaxf(acc1 + b_in[tid], 0.f), 1.f);
    __syncthreads();
    if (tid < 32) {
        float a = b_h1[tid];
        for (int j = 0; j < 512; ++j) a += xs[j] * w_h1[tid * 512 + j];
        h1s[tid] = fminf(fmaxf(a, 0.f), 1.f);
    }
    __syncthreads();
    if (tid < 32) {
        float a = b_h2[tid];
        for (int j = 0; j < 32; ++j) a += h1s[j] * w_h2[tid * 32 + j];
        h2s[tid] = fminf(fmaxf(a, 0.f), 1.f);
    }
    __syncthreads();
    if (tid == 0) {
        float a = b_out[0];
        for (int j = 0; j < 32; ++j) a += h2s[j] * w_out[j];
        out[b] = a;
    }
}

extern "C" void kernel_launch(void* const* d_in, const int* in_sizes, int n_in,
                              void* d_out, int out_size, void* d_ws, size_t ws_size,
                              hipStream_t stream)
{
    const float* white = (const float*)d_in[0];
    const float* black = (const float*)d_in[1];
    const float* w_in  = (const float*)d_in[2];
    const float* b_in  = (const float*)d_in[3];
    const float* w_h1  = (const float*)d_in[4];
    const float* b_h1  = (const float*)d_in[5];
    const float* w_h2  = (const float*)d_in[6];
    const float* b_h2  = (const float*)d_in[7];
    const float* w_out = (const float*)d_in[8];
    const float* b_out = (const float*)d_in[9];
    float* out = (float*)d_out;

    const size_t pF16 = KSPLIT * PSTRIDE * sizeof(_Float16);  // 32 MB

    if (ws_size >= pF16 + WWS_BYTES) {
        // f16 partials preferred: halves the P round-trip traffic.
        _Float16* Pp = (_Float16*)d_ws;
        _Float16* Wws = (_Float16*)((char*)d_ws + pF16);
        nnue_wprep<<<dim3(1280), 256, 0, stream>>>(w_in, Wws);
        nnue_gemm_v15<_Float16><<<dim3(512), 512, 0, stream>>>(white, black, Wws, Pp);
        nnue_tail<_Float16><<<dim3(128), 256, 0, stream>>>(Pp, b_in, w_h1, b_h1,
                                                           w_h2, b_h2, w_out, b_out, out);
    } else {
        nnue_naive<<<4096, 256, 0, stream>>>(white, black, w_in, b_in, w_h1, b_h1,
                                             w_h2, b_h2, w_out, b_out, out);
    }
}

// Round 18
// 371.315 us; speedup vs baseline: 1.6963x; 1.0242x over previous
//
#include <hip/hip_runtime.h>
#include <hip/hip_fp16.h>

// NNUE forward: out = MLP(clip(concat(Wf@w_in^T+b, Bf@w_in^T+b)))
// Big GEMM: M=8192, N=256, K=40960, HBM-bound on the 1.31 GB A stream.
// fp16 MFMA 16x16x32, f32 accumulate.
//
// FINAL (v16 = v11 restored, best measured: 372us, absmax 9.77e-4).
// r17 post-mortem: v15's f16-P + setprio were neutral-to-negative; per
// pre-commitment the lever space is exhausted:
//   falsified: burst length (v8), A-LDS (v9), barrier count (v10),
//   pipeline depth (v6), stream count (v12), nt/L2 policy (v13),
//   barrier-free (v14), f16-P+setprio (v15).
//   confirmed: K-phase rotation (+5%, v11).
// Achieved 372us = 1.55x the 240us mandatory-traffic floor; ~4.2 TB/s
// delivered. Residual gap = fabric behavior on 160KB-strided many-stream
// reads (linear fills do 6.6 TB/s); shape-pinned (wave must cover N=256).
//
// Structure: flatmm — wave = 16 M-rows x 256 N-cols (acc 16xf32x4);
// A global->VGPR->cvt(f16)->MFMA (no A-LDS); W pre-swizzled f16 image
// staged via global_load_lds into 4 x 16KB LDS bufs; 2 tiles per barrier
// group with counted vmcnt(4)+lgkmcnt(0) (W retired for cross-wave LDS
// visibility, A loads stay in flight); K-rotation t0=(mb*37)%160 de-phases
// DRAM channels; KS=8 -> 512 blocks (2/CU), ks=blockIdx&7 = XCD so each
// XCD's 64 blocks share one L2-resident 2.6MB W slice.

#define FEAT 40960
#define PSTRIDE (8192ull * 256ull)
#define KSPLIT 8
#define KCHUNK (FEAT / KSPLIT)   // 5120
#define NSTEP 160
#define WTILE_BYTES 16384        // 256 rows x 32 k x f16, swizzled
#define WWS_BYTES (1280ull * WTILE_BYTES)   // 20 MB

using floatx4 = __attribute__((ext_vector_type(4))) float;
using half8   = __attribute__((ext_vector_type(8))) _Float16;

// ---------------------------------------------------------------------------
// W pre-pass: w_in f32 [256][40960] -> Wws f16, 1280 chunks of 16 KB, each
// the exact swizzled LDS image for one K-step: byte(r, granule g) =
// T*16384 + r*64 + ((g ^ ((r>>1)&3))*16). T = ks*160 + t (ks-major).
// ---------------------------------------------------------------------------
__global__ __launch_bounds__(256) void nnue_wprep(
    const float* __restrict__ w_in, _Float16* __restrict__ Wws)
{
    const int bid = blockIdx.x;                       // 1280
    const int T   = (bid & 7) * NSTEP + (bid >> 3);
    char* base = (char*)Wws + (size_t)T * WTILE_BYTES;
    const int tid = threadIdx.x;
    const int kg0 = T * 32;
#pragma unroll
    for (int i = 0; i < 4; ++i) {
        const int G = tid + i * 256;                  // 0..1023
        const int r = G >> 2, g = G & 3;
        const float* src = w_in + (size_t)r * FEAT + kg0 + g * 8;
        floatx4 v0 = *reinterpret_cast<const floatx4*>(src);
        floatx4 v1 = *reinterpret_cast<const floatx4*>(src + 4);
        half8 h;
#pragma unroll
        for (int j = 0; j < 4; ++j) { h[j] = (_Float16)v0[j]; h[4 + j] = (_Float16)v1[j]; }
        *reinterpret_cast<half8*>(base + r * 64 + ((g ^ ((r >> 1) & 3)) << 4)) = h;
    }
}

// ---------------------------------------------------------------------------
// Primary GEMM: 512 thr = 8 waves, wave strip = 16 rows x 256 cols.
// ---------------------------------------------------------------------------
template <typename PT>
__global__ __launch_bounds__(512, 4) void nnue_gemm_v16(
    const float* __restrict__ white, const float* __restrict__ black,
    const _Float16* __restrict__ Wws, PT* __restrict__ P)
{
    __shared__ __align__(16) _Float16 Ws[4][256 * 32];   // 64 KB

    const int tid  = threadIdx.x;
    const int lane = tid & 63;
    const int wave = tid >> 6;    // 0..7

    const int ks = blockIdx.x & 7;    // == XCD index (round-robin dispatch)
    const int mb = blockIdx.x >> 3;   // 0..63

    const float* Abase = (mb < 32)
        ? (white + (size_t)mb * 128 * FEAT)
        : (black + (size_t)(mb - 32) * 128 * FEAT);

    // K-rotation phase: de-alias DRAM channels across blocks (+5%, r13).
    const int t0 = (mb * 37) % NSTEP;
    auto wrap = [](int x) { return (x >= NSTEP) ? x - NSTEP : x; };  // x < 2*NSTEP

    const int frow = lane & 15;
    const int fhi  = lane >> 4;

    // A: per-lane row = wave*16 + frow; tile t covers k = ks*KCHUNK + t*32
    const float* Aptr = Abase + (size_t)(wave * 16 + frow) * FEAT + fhi * 8
                        + ks * KCHUNK;

    // W LDS read byte offset within a row: (fhi*16) ^ (((frow>>1)&3)<<4)
    const int kb = (fhi * 16) ^ (((frow >> 1) & 3) << 4);

    // W async staging: per-lane global src (pre-swizzled), wave-linear LDS
    const char* wsrc0 = (const char*)Wws + (size_t)(ks * NSTEP) * WTILE_BYTES
                        + wave * 2048 + lane * 16;

    floatx4 acc[16];
    const floatx4 zero = {0.f, 0.f, 0.f, 0.f};
#pragma unroll
    for (int n = 0; n < 16; ++n) acc[n] = zero;

    // two statically-named A prefetch sets, each = one GROUP (2 tiles)
    floatx4 cA0, cA1, cA2, cA3, nA0, nA1, nA2, nA3;

    auto issueW = [&](int t, int wb) {               // t = wrapped tile index
        const char* g = wsrc0 + (size_t)t * WTILE_BYTES;
        char* l = (char*)&Ws[wb][0] + wave * 2048;
        __builtin_amdgcn_global_load_lds(
            (const __attribute__((address_space(1))) unsigned int*)g,
            (__attribute__((address_space(3))) unsigned int*)l, 16, 0, 0);
        __builtin_amdgcn_global_load_lds(
            (const __attribute__((address_space(1))) unsigned int*)(g + 1024),
            (__attribute__((address_space(3))) unsigned int*)(l + 1024), 16, 0, 0);
    };

    auto cvt = [&](const floatx4& a0, const floatx4& a1) {
        half8 h;
#pragma unroll
        for (int j = 0; j < 4; ++j) { h[j] = (_Float16)a0[j]; h[4 + j] = (_Float16)a1[j]; }
        return h;
    };

    auto mfmaStep = [&](int wb, half8 af) {
        const char* wbase = (const char*)&Ws[wb][0];
#pragma unroll
        for (int n = 0; n < 16; ++n) {
            half8 bf = *reinterpret_cast<const half8*>(
                wbase + (n * 16 + frow) * 64 + kb);
            acc[n] = __builtin_amdgcn_mfma_f32_16x16x32_f16(af, bf, acc[n], 0, 0, 0);
        }
    };

    // one group: consume 2 tiles (A in c*, W in rb0/rb1), prefetch the next
    // group's 2 tiles (tw0, tw1 wrapped) into wb0/wb1 and n*.
    auto groupf = [&](int tw0, int tw1,
                      floatx4& c0, floatx4& c1, floatx4& c2, floatx4& c3,
                      floatx4& n0, floatx4& n1, floatx4& n2, floatx4& n3,
                      int rb0, int rb1, int wb0, int wb1) {
        issueW(tw0, wb0);
        issueW(tw1, wb1);
        __builtin_amdgcn_sched_barrier(0);
        n0 = *reinterpret_cast<const floatx4*>(Aptr + (size_t)tw0 * 32);
        n1 = *reinterpret_cast<const floatx4*>(Aptr + (size_t)tw0 * 32 + 4);
        n2 = *reinterpret_cast<const floatx4*>(Aptr + (size_t)tw1 * 32);
        n3 = *reinterpret_cast<const floatx4*>(Aptr + (size_t)tw1 * 32 + 4);
        mfmaStep(rb0, cvt(c0, c1));            // cvt waits its A: counted vmcnt
        mfmaStep(rb1, cvt(c2, c3));
        // retire this group's W (cross-wave LDS visibility after the barrier);
        // keep the 4 A loads in flight across the barrier.
        asm volatile("s_waitcnt vmcnt(4) lgkmcnt(0)" ::: "memory");
        __builtin_amdgcn_s_barrier();
        __builtin_amdgcn_sched_barrier(0);
    };

    // prologue: tiles i=0,1 (wrapped) -> bufs 0,1 retired; their A in regs
    {
        const int p0 = t0;                 // wrap(t0) == t0
        const int p1 = wrap(t0 + 1);
        issueW(p0, 0);
        issueW(p1, 1);
        __builtin_amdgcn_sched_barrier(0);
        cA0 = *reinterpret_cast<const floatx4*>(Aptr + (size_t)p0 * 32);
        cA1 = *reinterpret_cast<const floatx4*>(Aptr + (size_t)p0 * 32 + 4);
        cA2 = *reinterpret_cast<const floatx4*>(Aptr + (size_t)p1 * 32);
        cA3 = *reinterpret_cast<const floatx4*>(Aptr + (size_t)p1 * 32 + 4);
        asm volatile("s_waitcnt vmcnt(4)" ::: "memory");   // W(i0),W(i1) retired
        __builtin_amdgcn_s_barrier();
        __builtin_amdgcn_sched_barrier(0);
    }

    // groups 0..77 (39 even/odd pairs); group g prefetches iterations 2g+2,2g+3
    for (int p = 0; p < 39; ++p) {
        const int i0 = 4 * p;
        groupf(wrap(t0 + i0 + 2), wrap(t0 + i0 + 3),
               cA0, cA1, cA2, cA3, nA0, nA1, nA2, nA3, 0, 1, 2, 3);
        groupf(wrap(t0 + i0 + 4), wrap(t0 + i0 + 5),
               nA0, nA1, nA2, nA3, cA0, cA1, cA2, cA3, 2, 3, 0, 1);
    }
    // group 78: reads bufs 0,1 (iters 156,157); prefetch iters 158,159
    groupf(wrap(t0 + 158), wrap(t0 + 159),
           cA0, cA1, cA2, cA3, nA0, nA1, nA2, nA3, 0, 1, 2, 3);
    // group 79 tail: iters 158 (buf 2), 159 (buf 3)
    mfmaStep(2, cvt(nA0, nA1));
    mfmaStep(3, cvt(nA2, nA3));

    // epilogue: partial C. row = wave*16 + fhi*4 + r, col = n*16 + frow
    PT* Pb = P + (size_t)ks * PSTRIDE + (size_t)mb * 128 * 256;
#pragma unroll
    for (int n = 0; n < 16; ++n)
#pragma unroll
        for (int r = 0; r < 4; ++r) {
            const int row = wave * 16 + fhi * 4 + r;
            const int col = n * 16 + frow;
            Pb[(size_t)row * 256 + col] = (PT)acc[n][r];
        }
}

// ---------------------------------------------------------------------------
// Tail: reduce KS partials + b_in + clip -> x[.,512], then the 3 tiny layers.
// One block per 32 batch rows.
// ---------------------------------------------------------------------------
template <typename PT>
__global__ __launch_bounds__(256) void nnue_tail(
    const PT* __restrict__ P,
    const float* __restrict__ b_in,
    const float* __restrict__ w_h1, const float* __restrict__ b_h1,
    const float* __restrict__ w_h2, const float* __restrict__ b_h2,
    const float* __restrict__ w_out, const float* __restrict__ b_out,
    float* __restrict__ out)
{
    __shared__ float xs[32][512];
    __shared__ float w1[32][513];
    __shared__ float w2[32][33];
    __shared__ float h1[32][33];
    __shared__ float h2[32][33];
    __shared__ float wo[32];

    const int tid = threadIdx.x;
    const int b0  = blockIdx.x * 32;

    for (int i = tid; i < 32 * 512; i += 256) w1[i >> 9][i & 511] = w_h1[i];
    for (int i = tid; i < 32 * 32; i += 256)  w2[i >> 5][i & 31]  = w_h2[i];
    if (tid < 32) wo[tid] = w_out[tid];

    for (int i = tid; i < 32 * 512; i += 256) {
        const int r = i >> 9, c = i & 511;
        const int persp = c >> 8, n = c & 255;
        const size_t prow = (size_t)(b0 + r) + (persp ? 4096u : 0u);
        float v = 0.f;
#pragma unroll
        for (int s = 0; s < KSPLIT; ++s)
            v += (float)P[(size_t)s * PSTRIDE + prow * 256 + n];
        v += b_in[n];
        xs[r][c] = fminf(fmaxf(v, 0.f), 1.f);
    }
    __syncthreads();

    for (int p = tid; p < 32 * 32; p += 256) {
        const int o = p & 31, r = p >> 5;
        float a = b_h1[o];
        for (int j = 0; j < 512; ++j) a += xs[r][j] * w1[o][j];
        h1[r][o] = fminf(fmaxf(a, 0.f), 1.f);
    }
    __syncthreads();

    for (int p = tid; p < 32 * 32; p += 256) {
        const int o = p & 31, r = p >> 5;
        float a = b_h2[o];
        for (int j = 0; j < 32; ++j) a += h1[r][j] * w2[o][j];
        h2[r][o] = fminf(fmaxf(a, 0.f), 1.f);
    }
    __syncthreads();

    if (tid < 32) {
        float a = b_out[0];
        for (int j = 0; j < 32; ++j) a += h2[tid][j] * wo[j];
        out[b0 + tid] = a;
    }
}

// ---------------------------------------------------------------------------
// Emergency fallback (ws too small): slow but correct, no scratch.
// ---------------------------------------------------------------------------
__global__ __launch_bounds__(256) void nnue_naive(
    const float* __restrict__ white, const float* __restrict__ black,
    const float* __restrict__ w_in, const float* __restrict__ b_in,
    const float* __restrict__ w_h1, const float* __restrict__ b_h1,
    const float* __restrict__ w_h2, const float* __restrict__ b_h2,
    const float* __restrict__ w_out, const float* __restrict__ b_out,
    float* __restrict__ out)
{
    __shared__ float feat[4096];
    __shared__ float xs[512];
    __shared__ float h1s[32];
    __shared__ float h2s[32];
    const int b = blockIdx.x, tid = threadIdx.x;
    float acc0 = 0.f, acc1 = 0.f;
    for (int c = 0; c < FEAT; c += 2048) {
        for (int i = tid; i < 2048; i += 256) {
            feat[i]        = white[(size_t)b * FEAT + c + i];
            feat[2048 + i] = black[(size_t)b * FEAT + c + i];
        }
        __syncthreads();
        const float* wr = w_in + (size_t)tid * FEAT + c;
        for (int k = 0; k < 2048; ++k) {
            const float w = wr[k];
            acc0 += feat[k] * w;
            acc1 += feat[2048 + k] * w;
        }
        __syncthreads();
    }
    xs[tid]       = fminf(fmaxf(acc0 + b_in[tid], 0.f), 1.f);
    xs[256 + tid] = fminf(fmaxf(acc1 + b_in[tid], 0.f), 1.f);
    __syncthreads();
    if (tid < 32) {
        float a = b_h1[tid];
        for (int j = 0; j < 512; ++j) a += xs[j] * w_h1[tid * 512 + j];
        h1s[tid] = fminf(fmaxf(a, 0.f), 1.f);
    }
    __syncthreads();
    if (tid < 32) {
        float a = b_h2[tid];
        for (int j = 0; j < 32; ++j) a += h1s[j] * w_h2[tid * 32 + j];
        h2s[tid] = fminf(fmaxf(a, 0.f), 1.f);
    }
    __syncthreads();
    if (tid == 0) {
        float a = b_out[0];
        for (int j = 0; j < 32; ++j) a += h2s[j] * w_out[j];
        out[b] = a;
    }
}

extern "C" void kernel_launch(void* const* d_in, const int* in_sizes, int n_in,
                              void* d_out, int out_size, void* d_ws, size_t ws_size,
                              hipStream_t stream)
{
    const float* white = (const float*)d_in[0];
    const float* black = (const float*)d_in[1];
    const float* w_in  = (const float*)d_in[2];
    const float* b_in  = (const float*)d_in[3];
    const float* w_h1  = (const float*)d_in[4];
    const float* b_h1  = (const float*)d_in[5];
    const float* w_h2  = (const float*)d_in[6];
    const float* b_h2  = (const float*)d_in[7];
    const float* w_out = (const float*)d_in[8];
    const float* b_out = (const float*)d_in[9];
    float* out = (float*)d_out;

    const size_t pF32 = KSPLIT * PSTRIDE * sizeof(float);     // 64 MB
    const size_t pF16 = KSPLIT * PSTRIDE * sizeof(_Float16);  // 32 MB

    if (ws_size >= pF32 + WWS_BYTES) {
        // Preferred: f32 partials (lowest absmax, best measured config).
        float* P = (float*)d_ws;
        _Float16* Wws = (_Float16*)((char*)d_ws + pF32);
        nnue_wprep<<<dim3(1280), 256, 0, stream>>>(w_in, Wws);
        nnue_gemm_v16<float><<<dim3(512), 512, 0, stream>>>(white, black, Wws, P);
        nnue_tail<float><<<dim3(128), 256, 0, stream>>>(P, b_in, w_h1, b_h1,
                                                        w_h2, b_h2, w_out, b_out, out);
    } else if (ws_size >= pF16 + WWS_BYTES) {
        _Float16* Pp = (_Float16*)d_ws;
        _Float16* Wws = (_Float16*)((char*)d_ws + pF16);
        nnue_wprep<<<dim3(1280), 256, 0, stream>>>(w_in, Wws);
        nnue_gemm_v16<_Float16><<<dim3(512), 512, 0, stream>>>(white, black, Wws, Pp);
        nnue_tail<_Float16><<<dim3(128), 256, 0, stream>>>(Pp, b_in, w_h1, b_h1,
                                                           w_h2, b_h2, w_out, b_out, out);
    } else {
        nnue_naive<<<4096, 256, 0, stream>>>(white, black, w_in, b_in, w_h1, b_h1,
                                             w_h2, b_h2, w_out, b_out, out);
    }
}